// Round 11
// baseline (2305.106 us; speedup 1.0000x reference)
//
#include <hip/hip_runtime.h>
#include <cstddef>
#include <cstdint>

typedef unsigned short u16;
typedef __attribute__((ext_vector_type(8))) unsigned short u16x8;
typedef __attribute__((ext_vector_type(8))) short s16x8;
typedef __attribute__((ext_vector_type(4))) float f32x4;

#define B_ 8
#define T_ 256
#define U_ 64
#define D_ 512
#define G_ 2048   // 4*DUNITS
#define OD 500
#define NBLK 136  // 128 LSTM + 8 attention blocks
#define NGRP 8    // barrier fan-in: 8 groups x 17 blocks

__device__ __forceinline__ float bf2f(u16 u){ unsigned v=((unsigned)u)<<16; return __builtin_bit_cast(float,v); }
__device__ __forceinline__ u16 f2bf(float f){ unsigned u=__builtin_bit_cast(unsigned,f); u += 0x7fffu + ((u>>16)&1u); return (u16)(u>>16); }
__device__ __forceinline__ float sigm(float x){ return 1.f/(1.f+expf(-x)); }
__device__ __forceinline__ float wredsum(float v){
  #pragma unroll
  for(int o=32;o;o>>=1) v += __shfl_xor(v,o);
  return v;
}
__device__ __forceinline__ float wredmax(float v){
  #pragma unroll
  for(int o=32;o;o>>=1) v = fmaxf(v,__shfl_xor(v,o));
  return v;
}

// coherent cross-block access (proven correct r5-r10).
__device__ __forceinline__ float gload(const float* p){
  return __hip_atomic_load(p, __ATOMIC_RELAXED, __HIP_MEMORY_SCOPE_AGENT);
}
__device__ __forceinline__ void gstore(float* p, float v){
  __hip_atomic_store(p, v, __ATOMIC_RELAXED, __HIP_MEMORY_SCOPE_AGENT);
}
// device-coherent 16B load; caller batches then waits once (rule #18).
__device__ __forceinline__ f32x4 gload4(const float* p){
  f32x4 r;
  asm volatile("global_load_dwordx4 %0, %1, off sc0 sc1" : "=v"(r) : "v"(p));
  return r;
}
#define GWAIT() do{ asm volatile("s_waitcnt vmcnt(0)":::"memory"); __builtin_amdgcn_sched_barrier(0); }while(0)

// leaderless two-level grid barrier: 8 arrival lines x 17 blocks; the 17th
// arrival of each group RMWs the root; everyone polls root only.
__device__ __forceinline__ void gridbar(unsigned* bar, int bid, unsigned gen){
  __syncthreads();
  if(threadIdx.x==0){
    asm volatile("s_waitcnt vmcnt(0)" ::: "memory");
    unsigned old=__hip_atomic_fetch_add(bar+((bid/17)<<5),1u,__ATOMIC_RELAXED,__HIP_MEMORY_SCOPE_AGENT);
    if(old==17u*gen-1u)
      __hip_atomic_fetch_add(bar+(NGRP<<5),1u,__ATOMIC_RELAXED,__HIP_MEMORY_SCOPE_AGENT);
    while(__hip_atomic_load(bar+(NGRP<<5),__ATOMIC_RELAXED,__HIP_MEMORY_SCOPE_AGENT) < (unsigned)NGRP*gen)
      __builtin_amdgcn_s_sleep(16);
  }
  __syncthreads();
}

// ---------------- conversion kernels (one-time per call) ----------------
__global__ void k_f2bf(const float* __restrict__ s, u16* __restrict__ d, int n){
  int i=blockIdx.x*256+threadIdx.x; if(i<n) d[i]=f2bf(s[i]);
}
__global__ void k_trans_bf(const float* __restrict__ s, u16* __restrict__ d, int R, int C){
  int i=blockIdx.x*256+threadIdx.x; if(i>=R*C) return;
  int c=i/R, r=i-c*R; d[i]=f2bf(s[(size_t)r*C+c]);
}
__global__ void k_woT(const float* __restrict__ W, u16* __restrict__ d){
  int i=blockIdx.x*256+threadIdx.x; if(i>=512*512) return;
  int o=i>>9, j=i&511; d[i] = (o<OD)? f2bf(W[(size_t)j*OD+o]) : (u16)0;
}
// peT[b][a][t] = pe_bf[b][t][a]  (coalesced-on-t layout for the e-phase)
__global__ void k_peT(const u16* __restrict__ s, u16* __restrict__ d){
  int i=blockIdx.x*256+threadIdx.x; if(i>=B_*512*T_) return;
  int t=i&255, a=(i>>8)&511, b=i>>17;
  d[i]=s[((size_t)(b*256+t))*512 + a];
}

// ---------------- generic bf16-MFMA GEMM (pre/post passes) ----------------
__global__ __launch_bounds__(256) void k_gemm(
  const float* __restrict__ A, const int* __restrict__ gidx, int lda,
  const float* __restrict__ Bm, int ldb, int bT,
  const float* __restrict__ bias1, const float* __restrict__ bias2,
  int actTanh, int outBf16, void* __restrict__ C, int ldc, int K)
{
  __shared__ __align__(16) u16 As[64][40];
  __shared__ __align__(16) u16 Bs[64][40];
  int tid=threadIdx.x;
  int m0=blockIdx.x*64, n0=blockIdx.y*64;
  int w=tid>>6, l=tid&63;
  f32x4 acc[4];
  #pragma unroll
  for(int nt=0;nt<4;++nt) acc[nt]=(f32x4){0.f,0.f,0.f,0.f};
  int arow=tid>>2, aseg=tid&3;
  int ar = gidx ? gidx[m0+arow] : (m0+arow);
  const float* Ap = A + (size_t)ar*lda + aseg*8;

  for(int kt=0;kt<K/32;++kt){
    const float* ap = Ap + kt*32;
    f32x4 a0=*(const f32x4*)ap, a1=*(const f32x4*)(ap+4);
    #pragma unroll
    for(int i=0;i<4;++i){ As[arow][aseg*8+i]=f2bf(a0[i]); As[arow][aseg*8+4+i]=f2bf(a1[i]); }
    if(bT){
      const float* bp = Bm + (size_t)(n0+arow)*ldb + kt*32 + aseg*8;
      f32x4 b0=*(const f32x4*)bp, b1=*(const f32x4*)(bp+4);
      #pragma unroll
      for(int i=0;i<4;++i){ Bs[arow][aseg*8+i]=f2bf(b0[i]); Bs[arow][aseg*8+4+i]=f2bf(b1[i]); }
    } else {
      int bk=tid>>3, bn=(tid&7)*8;
      const float* bp = Bm + (size_t)(kt*32+bk)*ldb + n0 + bn;
      f32x4 b0=*(const f32x4*)bp, b1=*(const f32x4*)(bp+4);
      #pragma unroll
      for(int i=0;i<4;++i){ Bs[bn+i][bk]=f2bf(b0[i]); Bs[bn+4+i][bk]=f2bf(b1[i]); }
    }
    __syncthreads();
    s16x8 af = *(const s16x8*)&As[w*16 + (l&15)][(l>>4)*8];
    #pragma unroll
    for(int nt=0;nt<4;++nt){
      s16x8 bf = *(const s16x8*)&Bs[nt*16 + (l&15)][(l>>4)*8];
      acc[nt]=__builtin_amdgcn_mfma_f32_16x16x32_bf16(af,bf,acc[nt],0,0,0);
    }
    __syncthreads();
  }
  int mr = w*16 + ((l>>4)<<2), cc = l&15;
  #pragma unroll
  for(int nt=0;nt<4;++nt){
    int gn = n0 + nt*16 + cc;
    float bb = (bias1?bias1[gn]:0.f) + (bias2?bias2[gn]:0.f);
    #pragma unroll
    for(int r=0;r<4;++r){
      int gm = m0 + mr + r;
      float v = acc[nt][r] + bb;
      if(actTanh) v = tanhf(v);
      if(outBf16) ((u16*)C)[(size_t)gm*ldc+gn] = f2bf(v);
      else        ((float*)C)[(size_t)gm*ldc+gn] = v;
    }
  }
}

// one 16(rows)x16(batch)xK matvec unit on MFMA (weights L2-hot, x-panel in LDS)
__device__ __forceinline__ f32x4 mfma_unit(const u16* __restrict__ Wb, const u16* xb,
                                           int lb, int l, int k0, int nks){
  int rl=l&15;
  int row = ((rl>>2)<<9) + (lb<<2) + (rl&3);
  const u16* wp = Wb + (size_t)row*512 + k0 + ((l>>4)*8);
  const u16* xp = xb + (size_t)rl*520 + k0 + ((l>>4)*8);
  f32x4 acc=(f32x4){0.f,0.f,0.f,0.f};
  for(int ks=0;ks<nks;++ks){
    s16x8 af=*(const s16x8*)(wp + ks*32);
    s16x8 bf=*(const s16x8*)(xp + ks*32);
    acc=__builtin_amdgcn_mfma_f32_16x16x32_bf16(af,bf,acc,0,0,0);
  }
  return acc;
}

// stage two 4096-float coherent arrays -> bf16 LDS panels [8][520]
__device__ __forceinline__ void stage_panel2(const float* s0, u16* d0,
                                             const float* s1, u16* d1, int tid){
  int base=tid*16;
  const float* pa=s0+base; const float* pb=s1+base;
  f32x4 a0=gload4(pa), a1=gload4(pa+4), a2=gload4(pa+8), a3=gload4(pa+12);
  f32x4 b0=gload4(pb), b1=gload4(pb+4), b2=gload4(pb+8), b3=gload4(pb+12);
  GWAIT();
  int bb=tid>>5, kk=base&511;
  u16* dx=d0+bb*520+kk; u16* dh=d1+bb*520+kk;
  u16x8 w0,w1,w2,w3;
  #pragma unroll
  for(int i=0;i<4;++i){
    w0[i]=f2bf(a0[i]); w0[4+i]=f2bf(a1[i]); w1[i]=f2bf(a2[i]); w1[4+i]=f2bf(a3[i]);
    w2[i]=f2bf(b0[i]); w2[4+i]=f2bf(b1[i]); w3[i]=f2bf(b2[i]); w3[4+i]=f2bf(b3[i]);
  }
  *(u16x8*)dx=w0; *(u16x8*)(dx+8)=w1;
  *(u16x8*)dh=w2; *(u16x8*)(dh+8)=w3;
}

// ---------------- persistent scan kernel ----------------
// 136 blocks x 256 thr, 2 grid barriers/step:
//  X: LSTM blocks 0..127: LSTM1(u-1)+Whh0 partial on MFMA.
//     attn blocks 128..135 (one per b): q -> e -> exact softmax -> publish w.
//  Z: LSTM blocks: gates0 = ey_pre + gpart + sum_t w[b][t]*hsWi0[row][b][t].
//     (attc eliminated via attc@Wi0a^T == w@(hs@Wi0a^T), hsWi0 precomputed)
__global__ __launch_bounds__(256) void k_scan(
  const u16* __restrict__ WdT, const float* __restrict__ b_att_dec,
  const u16* __restrict__ peT, const int* __restrict__ hlens,
  const u16* __restrict__ hsWi0T, const u16* __restrict__ Whh0b,
  const u16* __restrict__ Wih1b, const u16* __restrict__ Whh1b,
  const float* __restrict__ b_ih1, const float* __restrict__ b_hh1,
  const float* __restrict__ ey_pre, float* __restrict__ w_g,
  float* __restrict__ h0g, float* __restrict__ h1g,
  float* __restrict__ hdec, unsigned* __restrict__ barcnt)
{
  __shared__ __align__(16) char smraw[47872];
  int tid=threadIdx.x, bid=blockIdx.x;
  unsigned baridx=0;

  if(bid<128){
    int lb=bid, w=tid>>6, l=tid&63;
    u16*  xbf=(u16*)smraw;               // 16x520 bf16 h0 panel
    u16*  hbf=(u16*)(smraw+16640);       // 16x520 bf16 h1prev panel
    float* gl=(float*)(smraw+33280);     // [4][16][16] C-frag dump
    float* gp=(float*)(smraw+37376);     // [16][16] Whh0 partial (survives bar)
    float* w_lds=(float*)(smraw+38400);  // [8][260] softmax weights (padded)
    float* zres=(float*)(smraw+46720);   // [256] weighted-sum halves
    for(int i=tid;i<16*520;i+=256){ xbf[i]=0; hbf[i]=0; }  // cols 8..15 stay 0
    float c0r=0.f, c1r=0.f;
    int jj=(tid>>3)&3, b=tid&7;          // epilogue cell for tid<32

    for(int u=0;u<=U_;++u){
      float* h1prev=h1g+(u&1)*4096;
      float* h1new =h1g+((u+1)&1)*4096;
      // ---- X: stage h0,h1prev; MFMA Wih1/Whh1/Whh0; h1 epilogue ----
      stage_panel2(h0g,xbf,h1prev,hbf,tid);
      __syncthreads();
      f32x4 acc;
      if(w==0)      acc=mfma_unit(Wih1b,xbf,lb,l,0,16);
      else if(w==1) acc=mfma_unit(Whh1b,hbf,lb,l,0,16);
      else if(w==2) acc=mfma_unit(Whh0b,xbf,lb,l,0,8);
      else          acc=mfma_unit(Whh0b,xbf,lb,l,256,8);
      {
        float* gld=gl+w*256;
        #pragma unroll
        for(int r=0;r<4;++r) gld[((l>>4)*4+r)*16+(l&15)]=acc[r];
      }
      __syncthreads();
      gp[tid]=gl[512+tid]+gl[768+tid];      // Whh0 k-halves combined
      if(u>0 && tid<32){
        int j=lb*4+jj;
        float gv[4];
        #pragma unroll
        for(int g=0;g<4;++g){
          int ridx=g*4+jj, row=g*512+j;
          gv[g]=gl[ridx*16+b]+gl[256+ridx*16+b]+b_ih1[row]+b_hh1[row];
        }
        float i_=sigm(gv[0]), f_=sigm(gv[1]), g_=tanhf(gv[2]), o_=sigm(gv[3]);
        c1r=f_*c1r+i_*g_;
        float h=o_*tanhf(c1r);
        gstore(h1new+b*512+j,h);
        hdec[((size_t)(b*64+(u-1)))*512+j]=h;
      }
      if(u==U_) break;
      gridbar(barcnt,bid,++baridx);   // X -> Z

      // ---- Z: LSTM0 via w-weighted hsWi0 sum ----
      {
        int idx=tid*8, wb2=idx>>8, wt=idx&255;
        f32x4 v0=gload4(w_g+idx), v1=gload4(w_g+idx+4);
        GWAIT();
        float* d=w_lds+wb2*260+wt;
        *(f32x4*)d=v0; *(f32x4*)(d+4)=v1;
      }
      __syncthreads();
      {
        int out=tid>>1, half=tid&1;
        int ridx=out>>3, bb=out&7;
        int rowg=(ridx>>2)*512 + lb*4 + (ridx&3);
        const u16* hp=hsWi0T+(size_t)rowg*2048 + bb*256 + half*128;
        const float* wl=w_lds + bb*260 + half*128;
        float p0=0.f,p1=0.f,p2=0.f,p3=0.f;
        #pragma unroll
        for(int i=0;i<16;++i){
          u16x8 v=*(const u16x8*)(hp+i*8);
          f32x4 wa=*(const f32x4*)(wl+i*8), wb4=*(const f32x4*)(wl+i*8+4);
          p0+=wa[0]*bf2f(v[0])+wa[2]*bf2f(v[2]);
          p1+=wa[1]*bf2f(v[1])+wa[3]*bf2f(v[3]);
          p2+=wb4[0]*bf2f(v[4])+wb4[2]*bf2f(v[6]);
          p3+=wb4[1]*bf2f(v[5])+wb4[3]*bf2f(v[7]);
        }
        zres[tid]=(p0+p1)+(p2+p3);
      }
      __syncthreads();
      if(tid<32){
        int j=lb*4+jj;
        float gv[4];
        #pragma unroll
        for(int g=0;g<4;++g){
          int ridx=g*4+jj, row=g*512+j, out=ridx*8+b;
          gv[g]=zres[out*2]+zres[out*2+1]+gp[ridx*16+b]
               +ey_pre[((size_t)((b<<6)|u))*2048+row];
        }
        float i_=sigm(gv[0]), f_=sigm(gv[1]), g_=tanhf(gv[2]), o_=sigm(gv[3]);
        c0r=f_*c0r+i_*g_;
        gstore(h0g+b*512+j,o_*tanhf(c0r));
      }
      gridbar(barcnt,bid,++baridx);   // Z -> next X
    }
  } else {
    // ---- attention block, batch b: q -> e -> softmax -> w ----
    int b=bid-128;
    float* h0s=(float*)smraw;            // 512 f
    float* qs =(float*)(smraw+2048);     // 512 f
    float* red=(float*)(smraw+4096);     // 16 f
    int wv=tid>>6, ln=tid&63;
    int hl=hlens[b];
    for(int u=0;u<=U_;++u){
      if(u<U_){
        if(tid<128){
          f32x4 v=gload4(h0g+b*512+tid*4);
          GWAIT();
          *(f32x4*)(h0s+tid*4)=v;
        }
        __syncthreads();
        // q = tanh(WdT @ h0 + b): 2 rows/thread, WdT slice L2-hot
        #pragma unroll
        for(int rep=0;rep<2;++rep){
          int a_=tid+rep*256;
          const u16* wr=WdT+(size_t)a_*512;
          float p0=0.f,p1=0.f,p2=0.f,p3=0.f;
          for(int kc=0;kc<64;++kc){
            u16x8 v=*(const u16x8*)(wr+kc*8);
            f32x4 xa=*(const f32x4*)(h0s+kc*8), xb2=*(const f32x4*)(h0s+kc*8+4);
            p0+=bf2f(v[0])*xa[0]+bf2f(v[2])*xa[2];
            p1+=bf2f(v[1])*xa[1]+bf2f(v[3])*xa[3];
            p2+=bf2f(v[4])*xb2[0]+bf2f(v[6])*xb2[2];
            p3+=bf2f(v[5])*xb2[1]+bf2f(v[7])*xb2[3];
          }
          qs[a_]=tanhf((p0+p1)+(p2+p3)+b_att_dec[a_]);
        }
        __syncthreads();
        // e[t=tid] (coalesced peT), exact softmax, publish w
        {
          const u16* pT=peT+(size_t)b*131072 + tid;
          float e0=0.f,e1=0.f,e2=0.f,e3=0.f;
          for(int a=0;a<512;a+=4){
            f32x4 q4=*(const f32x4*)(qs+a);
            e0+=q4[0]*bf2f(pT[(size_t)(a  )*256]);
            e1+=q4[1]*bf2f(pT[(size_t)(a+1)*256]);
            e2+=q4[2]*bf2f(pT[(size_t)(a+2)*256]);
            e3+=q4[3]*bf2f(pT[(size_t)(a+3)*256]);
          }
          float val=(tid<hl)? (e0+e1)+(e2+e3) : -1e30f;
          float m=wredmax(val);
          if(ln==0) red[wv]=m;
          __syncthreads();
          float M=fmaxf(fmaxf(red[0],red[1]),fmaxf(red[2],red[3]));
          float p=expf(val-M);
          float s=wredsum(p);
          if(ln==0) red[4+wv]=s;
          __syncthreads();
          float S=red[4]+red[5]+red[6]+red[7];
          gstore(w_g+b*256+tid, p/S);
        }
      }
      if(u==U_) break;
      gridbar(barcnt,bid,++baridx);   // X -> Z
      gridbar(barcnt,bid,++baridx);   // Z -> next X (attn idle in Z)
    }
  }
}

// ---------------- joint network ----------------
// 32-row t-tiles (33KB LDS -> 2 blocks/CU for latency hiding)
__global__ __launch_bounds__(256) void k_joint(
  const float* __restrict__ lin_enc, const float* __restrict__ lin_dec,
  const u16* __restrict__ WoT, const float* __restrict__ b_out,
  float* __restrict__ out)
{
  __shared__ __align__(16) u16 As[32*512];
  __shared__ float ld_s[512];
  int tid=threadIdx.x, bid=blockIdx.x;
  int b=bid>>9, u=(bid>>3)&63, t0=(bid&7)*32;
  for(int i=tid;i<512;i+=256) ld_s[i]=lin_dec[((size_t)((b<<6)|u))*512 + i];
  __syncthreads();
  const float* le = lin_enc + ((size_t)(b*256 + t0))*512;
  for(int it=0;it<8;++it){
    int idx=it*256+tid;
    int row=idx>>6, c0=(idx&63)*8;
    f32x4 x0=*(const f32x4*)(le + (size_t)row*512 + c0);
    f32x4 x1=*(const f32x4*)(le + (size_t)row*512 + c0 + 4);
    u16x8 pk;
    #pragma unroll
    for(int i=0;i<4;++i){
      pk[i]  =f2bf(tanhf(x0[i]+ld_s[c0+i]));
      pk[4+i]=f2bf(tanhf(x1[i]+ld_s[c0+4+i]));
    }
    int sc = c0 ^ ((row&7)<<3);
    *(u16x8*)&As[row*512+sc]=pk;
  }
  __syncthreads();
  int w=tid>>6, l=tid&63;
  for(int ch=0;ch<8;++ch){
    int n0=ch*64 + w*16;
    int o = n0 + (l&15);
    s16x8 bfr[16];
    const u16* wp = WoT + (size_t)o*512 + ((l>>4)*8);
    #pragma unroll
    for(int ks=0;ks<16;++ks) bfr[ks]=*(const s16x8*)(wp + ks*32);
    float bo = (o<OD)? b_out[o] : 0.f;
    #pragma unroll
    for(int mt=0;mt<2;++mt){
      f32x4 acc=(f32x4){0.f,0.f,0.f,0.f};
      int row = mt*16 + (l&15);
      int sw  = (row&7)<<3;
      #pragma unroll
      for(int ks=0;ks<16;++ks){
        int cidx=(ks*32 + (l>>4)*8) ^ sw;
        s16x8 af=*(const s16x8*)&As[row*512+cidx];
        acc=__builtin_amdgcn_mfma_f32_16x16x32_bf16(af,bfr[ks],acc,0,0,0);
      }
      if(o<OD){
        #pragma unroll
        for(int r=0;r<4;++r){
          int t = t0 + mt*16 + ((l>>4)<<2) + r;
          out[(((size_t)(b*256+t))*64 + u)*500 + o] = acc[r] + bo;
        }
      }
    }
  }
}

// ---------------- host launcher ----------------
extern "C" void kernel_launch(void* const* d_in, const int* in_sizes, int n_in,
                              void* d_out, int out_size, void* d_ws, size_t ws_size,
                              hipStream_t stream)
{
  (void)in_sizes; (void)n_in; (void)out_size; (void)ws_size;
  const float* hs_pad   =(const float*)d_in[0];
  const int*   ys       =(const int*)  d_in[1];
  const int*   hlens    =(const int*)  d_in[2];
  const float* emb      =(const float*)d_in[3];
  const float* W_ih0    =(const float*)d_in[4];
  const float* W_hh0    =(const float*)d_in[5];
  const float* b_ih0    =(const float*)d_in[6];
  const float* b_hh0    =(const float*)d_in[7];
  const float* W_ih1    =(const float*)d_in[8];
  const float* W_hh1    =(const float*)d_in[9];
  const float* b_ih1    =(const float*)d_in[10];
  const float* b_hh1    =(const float*)d_in[11];
  const float* W_att_enc=(const float*)d_in[12];
  const float* b_att_enc=(const float*)d_in[13];
  const float* W_att_dec=(const float*)d_in[14];
  const float* b_att_dec=(const float*)d_in[15];
  const float* W_lin_enc=(const float*)d_in[16];
  const float* b_lin_enc=(const float*)d_in[17];
  const float* W_lin_dec=(const float*)d_in[18];
  const float* W_out    =(const float*)d_in[19];
  const float* b_out    =(const float*)d_in[20];
  float* out=(float*)d_out;

  char* wp=(char*)d_ws;
  auto carve=[&](size_t bytes)->char*{ char* p=wp; wp += (bytes+255)&~(size_t)255; return p; };
  u16*   pe_bf  =(u16*)  carve((size_t)B_*T_*D_*2);
  u16*   peT    =(u16*)  carve((size_t)B_*D_*T_*2);
  u16*   WdT    =(u16*)  carve((size_t)512*512*2);
  u16*   Whh0b  =(u16*)  carve((size_t)G_*512*2);
  u16*   Wih1b  =(u16*)  carve((size_t)G_*512*2);
  u16*   Whh1b  =(u16*)  carve((size_t)G_*512*2);
  u16*   WoT    =(u16*)  carve((size_t)512*512*2);
  u16*   hsWi0T =(u16*)  carve((size_t)G_*B_*T_*2);   // [row][b*256+t] bf16, 8MB
  float* lin_enc=(float*)carve((size_t)B_*T_*512*4);
  float* ey_pre =(float*)carve((size_t)B_*U_*G_*4);
  float* hdec   =(float*)carve((size_t)B_*U_*512*4);
  float* lin_dec=(float*)carve((size_t)B_*U_*512*4);
  float* w_g    =(float*)carve((size_t)B_*T_*4);
  float* states =(float*)carve(3*4096*4);
  unsigned* barcnt=(unsigned*)carve(2048);
  float* h0g=states;            // 4096
  float* h1g=states+4096;       // 2 x 4096 (ping-pong)

  hipMemsetAsync(states,0,3*4096*4,stream);
  hipMemsetAsync(barcnt,0,2048,stream);

  int n2=G_*512;
  k_trans_bf<<<(512*512+255)/256,256,0,stream>>>(W_att_dec,WdT,512,512);
  k_f2bf    <<<(n2+255)/256,256,0,stream>>>(W_hh0,Whh0b,n2);
  k_f2bf    <<<(n2+255)/256,256,0,stream>>>(W_ih1,Wih1b,n2);
  k_f2bf    <<<(n2+255)/256,256,0,stream>>>(W_hh1,Whh1b,n2);
  k_woT     <<<(512*512+255)/256,256,0,stream>>>(W_out,WoT);

  // pre GEMMs
  k_gemm<<<dim3(32,8),256,0,stream>>>(hs_pad,nullptr,512, W_att_enc,512,0, b_att_enc,nullptr, 1,1, pe_bf,512, 512);
  k_peT <<<(B_*512*T_+255)/256,256,0,stream>>>(pe_bf,peT);
  k_gemm<<<dim3(32,8),256,0,stream>>>(hs_pad,nullptr,512, W_lin_enc,512,0, b_lin_enc,nullptr, 0,0, lin_enc,512, 512);
  k_gemm<<<dim3(8,32),256,0,stream>>>(emb,ys,512,        W_ih0,1024,1,    b_ih0,b_hh0,      0,0, ey_pre,2048, 512);
  // hsWi0T[row][b,t] = W_ih0[row][512:1024] . hs_pad[b,t,:]  (M=2048,N=2048,K=512)
  k_gemm<<<dim3(32,32),256,0,stream>>>(W_ih0+512,nullptr,1024, hs_pad,512,1, nullptr,nullptr, 0,1, hsWi0T,2048, 512);

  // persistent scan: one launch for all 64 steps
  k_scan<<<NBLK,256,0,stream>>>(WdT,b_att_dec,peT,hlens,
                                hsWi0T,Whh0b,Wih1b,Whh1b,b_ih1,b_hh1,ey_pre,
                                w_g,h0g,h1g,hdec,barcnt);

  // post GEMM + joint
  k_gemm <<<dim3(8,8),256,0,stream>>>(hdec,nullptr,512, W_lin_dec,512,0, nullptr,nullptr, 0,0, lin_dec,512, 512);
  k_joint<<<4096,256,0,stream>>>(lin_enc,lin_dec,WoT,b_out,out);
}

// Round 12
// 1233.267 us; speedup vs baseline: 1.8691x; 1.8691x over previous
//
#include <hip/hip_runtime.h>
#include <cstddef>
#include <cstdint>

typedef unsigned short u16;
typedef __attribute__((ext_vector_type(8))) unsigned short u16x8;
typedef __attribute__((ext_vector_type(8))) short s16x8;
typedef __attribute__((ext_vector_type(4))) float f32x4;

#define B_ 8
#define T_ 256
#define U_ 64
#define D_ 512
#define G_ 2048   // 4*DUNITS
#define OD 500
#define NBLK 192  // 128 LSTM + 64 attention blocks
#define NGRP 12   // barrier fan-in: 12 groups x 16

__device__ __forceinline__ float bf2f(u16 u){ unsigned v=((unsigned)u)<<16; return __builtin_bit_cast(float,v); }
__device__ __forceinline__ u16 f2bf(float f){ unsigned u=__builtin_bit_cast(unsigned,f); u += 0x7fffu + ((u>>16)&1u); return (u16)(u>>16); }
__device__ __forceinline__ float sigm(float x){ return 1.f/(1.f+expf(-x)); }
__device__ __forceinline__ float wredsum(float v){
  #pragma unroll
  for(int o=32;o;o>>=1) v += __shfl_xor(v,o);
  return v;
}
__device__ __forceinline__ float wredmax(float v){
  #pragma unroll
  for(int o=32;o;o>>=1) v = fmaxf(v,__shfl_xor(v,o));
  return v;
}
// width-32 variants (stay within a 32-lane half)
__device__ __forceinline__ float wredsum32(float v){
  #pragma unroll
  for(int o=16;o;o>>=1) v += __shfl_xor(v,o);
  return v;
}
__device__ __forceinline__ float wredmax32(float v){
  #pragma unroll
  for(int o=16;o;o>>=1) v = fmaxf(v,__shfl_xor(v,o));
  return v;
}

// coherent cross-block access (proven correct r5-r11).
__device__ __forceinline__ float gload(const float* p){
  return __hip_atomic_load(p, __ATOMIC_RELAXED, __HIP_MEMORY_SCOPE_AGENT);
}
__device__ __forceinline__ void gstore(float* p, float v){
  __hip_atomic_store(p, v, __ATOMIC_RELAXED, __HIP_MEMORY_SCOPE_AGENT);
}
// device-coherent 16B load; caller batches then waits once (rule #18).
__device__ __forceinline__ f32x4 gload4(const float* p){
  f32x4 r;
  asm volatile("global_load_dwordx4 %0, %1, off sc0 sc1" : "=v"(r) : "v"(p));
  return r;
}
#define GWAIT() do{ asm volatile("s_waitcnt vmcnt(0)":::"memory"); __builtin_amdgcn_sched_barrier(0); }while(0)

// leaderless two-level grid barrier: 12 arrival lines x 16 blocks; the 16th
// arrival of each group RMWs the root; everyone polls root only.
__device__ __forceinline__ void gridbar(unsigned* bar, int bid, unsigned gen){
  __syncthreads();
  if(threadIdx.x==0){
    asm volatile("s_waitcnt vmcnt(0)" ::: "memory");
    unsigned old=__hip_atomic_fetch_add(bar+((bid>>4)<<5),1u,__ATOMIC_RELAXED,__HIP_MEMORY_SCOPE_AGENT);
    if(old==16u*gen-1u)
      __hip_atomic_fetch_add(bar+(NGRP<<5),1u,__ATOMIC_RELAXED,__HIP_MEMORY_SCOPE_AGENT);
    while(__hip_atomic_load(bar+(NGRP<<5),__ATOMIC_RELAXED,__HIP_MEMORY_SCOPE_AGENT) < (unsigned)NGRP*gen)
      __builtin_amdgcn_s_sleep(16);
  }
  __syncthreads();
}

// ---------------- conversion kernels (one-time per call) ----------------
__global__ void k_f2bf(const float* __restrict__ s, u16* __restrict__ d, int n){
  int i=blockIdx.x*256+threadIdx.x; if(i<n) d[i]=f2bf(s[i]);
}
__global__ void k_trans_bf(const float* __restrict__ s, u16* __restrict__ d, int R, int C){
  int i=blockIdx.x*256+threadIdx.x; if(i>=R*C) return;
  int c=i/R, r=i-c*R; d[i]=f2bf(s[(size_t)r*C+c]);
}
__global__ void k_woT(const float* __restrict__ W, u16* __restrict__ d){
  int i=blockIdx.x*256+threadIdx.x; if(i>=512*512) return;
  int o=i>>9, j=i&511; d[i] = (o<OD)? f2bf(W[(size_t)j*OD+o]) : (u16)0;
}
// peT[b][a][t] = pe_bf[b][t][a]  (coalesced-on-t layout for the e-phase)
__global__ void k_peT(const u16* __restrict__ s, u16* __restrict__ d){
  int i=blockIdx.x*256+threadIdx.x; if(i>=B_*512*T_) return;
  int t=i&255, a=(i>>8)&511, b=i>>17;
  d[i]=s[((size_t)(b*256+t))*512 + a];
}

// ---------------- generic bf16-MFMA GEMM (pre/post passes) ----------------
__global__ __launch_bounds__(256) void k_gemm(
  const float* __restrict__ A, const int* __restrict__ gidx, int lda,
  const float* __restrict__ Bm, int ldb, int bT,
  const float* __restrict__ bias1, const float* __restrict__ bias2,
  int actTanh, int outBf16, void* __restrict__ C, int ldc, int K)
{
  __shared__ __align__(16) u16 As[64][40];
  __shared__ __align__(16) u16 Bs[64][40];
  int tid=threadIdx.x;
  int m0=blockIdx.x*64, n0=blockIdx.y*64;
  int w=tid>>6, l=tid&63;
  f32x4 acc[4];
  #pragma unroll
  for(int nt=0;nt<4;++nt) acc[nt]=(f32x4){0.f,0.f,0.f,0.f};
  int arow=tid>>2, aseg=tid&3;
  int ar = gidx ? gidx[m0+arow] : (m0+arow);
  const float* Ap = A + (size_t)ar*lda + aseg*8;

  for(int kt=0;kt<K/32;++kt){
    const float* ap = Ap + kt*32;
    f32x4 a0=*(const f32x4*)ap, a1=*(const f32x4*)(ap+4);
    #pragma unroll
    for(int i=0;i<4;++i){ As[arow][aseg*8+i]=f2bf(a0[i]); As[arow][aseg*8+4+i]=f2bf(a1[i]); }
    if(bT){
      const float* bp = Bm + (size_t)(n0+arow)*ldb + kt*32 + aseg*8;
      f32x4 b0=*(const f32x4*)bp, b1=*(const f32x4*)(bp+4);
      #pragma unroll
      for(int i=0;i<4;++i){ Bs[arow][aseg*8+i]=f2bf(b0[i]); Bs[arow][aseg*8+4+i]=f2bf(b1[i]); }
    } else {
      int bk=tid>>3, bn=(tid&7)*8;
      const float* bp = Bm + (size_t)(kt*32+bk)*ldb + n0 + bn;
      f32x4 b0=*(const f32x4*)bp, b1=*(const f32x4*)(bp+4);
      #pragma unroll
      for(int i=0;i<4;++i){ Bs[bn+i][bk]=f2bf(b0[i]); Bs[bn+4+i][bk]=f2bf(b1[i]); }
    }
    __syncthreads();
    s16x8 af = *(const s16x8*)&As[w*16 + (l&15)][(l>>4)*8];
    #pragma unroll
    for(int nt=0;nt<4;++nt){
      s16x8 bf = *(const s16x8*)&Bs[nt*16 + (l&15)][(l>>4)*8];
      acc[nt]=__builtin_amdgcn_mfma_f32_16x16x32_bf16(af,bf,acc[nt],0,0,0);
    }
    __syncthreads();
  }
  int mr = w*16 + ((l>>4)<<2), cc = l&15;
  #pragma unroll
  for(int nt=0;nt<4;++nt){
    int gn = n0 + nt*16 + cc;
    float bb = (bias1?bias1[gn]:0.f) + (bias2?bias2[gn]:0.f);
    #pragma unroll
    for(int r=0;r<4;++r){
      int gm = m0 + mr + r;
      float v = acc[nt][r] + bb;
      if(actTanh) v = tanhf(v);
      if(outBf16) ((u16*)C)[(size_t)gm*ldc+gn] = f2bf(v);
      else        ((float*)C)[(size_t)gm*ldc+gn] = v;
    }
  }
}

// one 16(rows)x16(batch)xK matvec unit on MFMA (weights L2-hot, x-panel in LDS)
__device__ __forceinline__ f32x4 mfma_unit(const u16* __restrict__ Wb, const u16* xb,
                                           int lb, int l, int k0, int nks){
  int rl=l&15;
  int row = ((rl>>2)<<9) + (lb<<2) + (rl&3);
  const u16* wp = Wb + (size_t)row*512 + k0 + ((l>>4)*8);
  const u16* xp = xb + (size_t)rl*520 + k0 + ((l>>4)*8);
  f32x4 acc=(f32x4){0.f,0.f,0.f,0.f};
  for(int ks=0;ks<nks;++ks){
    s16x8 af=*(const s16x8*)(wp + ks*32);
    s16x8 bf=*(const s16x8*)(xp + ks*32);
    acc=__builtin_amdgcn_mfma_f32_16x16x32_bf16(af,bf,acc,0,0,0);
  }
  return acc;
}

// stage two 4096-float coherent arrays -> bf16 LDS panels [8][520]
__device__ __forceinline__ void stage_panel2(const float* s0, u16* d0,
                                             const float* s1, u16* d1, int tid){
  int base=tid*16;
  const float* pa=s0+base; const float* pb=s1+base;
  f32x4 a0=gload4(pa), a1=gload4(pa+4), a2=gload4(pa+8), a3=gload4(pa+12);
  f32x4 b0=gload4(pb), b1=gload4(pb+4), b2=gload4(pb+8), b3=gload4(pb+12);
  GWAIT();
  int bb=tid>>5, kk=base&511;
  u16* dx=d0+bb*520+kk; u16* dh=d1+bb*520+kk;
  u16x8 w0,w1,w2,w3;
  #pragma unroll
  for(int i=0;i<4;++i){
    w0[i]=f2bf(a0[i]); w0[4+i]=f2bf(a1[i]); w1[i]=f2bf(a2[i]); w1[4+i]=f2bf(a3[i]);
    w2[i]=f2bf(b0[i]); w2[4+i]=f2bf(b1[i]); w3[i]=f2bf(b2[i]); w3[4+i]=f2bf(b3[i]);
  }
  *(u16x8*)dx=w0; *(u16x8*)(dx+8)=w1;
  *(u16x8*)dh=w2; *(u16x8*)(dh+8)=w3;
}

// ---------------- persistent scan kernel ----------------
// 192 blocks x 256 thr, 2 grid barriers/step:
//  X: LSTM blocks 0..127: LSTM1(u-1)+Whh0 partial on MFMA.
//     attn blocks 128..191 (b, a-chunk): q-chunk + e-partials (L2-hot slices).
//  Z: LSTM blocks: combine e-partials + REDUNDANT in-block softmax -> w_lds,
//     then gates0 = ey_pre + gpart + sum_t w[b][t]*hsWi0[row][b][t].
//     (attc eliminated via attc@Wi0a^T == w@(hs@Wi0a^T); attn blocks idle)
__global__ __launch_bounds__(256) void k_scan(
  const u16* __restrict__ WdT, const float* __restrict__ b_att_dec,
  const u16* __restrict__ peT, const int* __restrict__ hlens,
  const u16* __restrict__ hsWi0T, const u16* __restrict__ Whh0b,
  const u16* __restrict__ Wih1b, const u16* __restrict__ Whh1b,
  const float* __restrict__ b_ih1, const float* __restrict__ b_hh1,
  const float* __restrict__ ey_pre, float* __restrict__ e_part,
  float* __restrict__ h0g, float* __restrict__ h1g,
  float* __restrict__ hdec, unsigned* __restrict__ barcnt)
{
  __shared__ __align__(16) char smraw[47872];
  int tid=threadIdx.x, bid=blockIdx.x;
  unsigned baridx=0;

  if(bid<128){
    int lb=bid, w=tid>>6, l=tid&63;
    u16*  xbf=(u16*)smraw;               // 16x520 bf16 h0 panel
    u16*  hbf=(u16*)(smraw+16640);       // 16x520 bf16 h1prev panel
    float* gl=(float*)(smraw+33280);     // [4][16][16] C-frag dump
    float* gp=(float*)(smraw+37376);     // [16][16] Whh0 partial (survives bar)
    float* w_lds=(float*)(smraw+38400);  // [8][260] softmax weights (padded)
    float* zres=(float*)(smraw+46720);   // [256] weighted-sum halves
    for(int i=tid;i<16*520;i+=256){ xbf[i]=0; hbf[i]=0; }  // cols 8..15 stay 0
    float c0r=0.f, c1r=0.f;
    int jj=(tid>>3)&3, b=tid&7;          // epilogue cell for tid<32
    int sb=tid>>5, ln2=tid&31;           // softmax: batch sb, 8 t's per thread
    int hl_sb=hlens[sb];

    for(int u=0;u<=U_;++u){
      float* h1prev=h1g+(u&1)*4096;
      float* h1new =h1g+((u+1)&1)*4096;
      // ---- X: stage h0,h1prev; MFMA Wih1/Whh1/Whh0; h1 epilogue ----
      stage_panel2(h0g,xbf,h1prev,hbf,tid);
      __syncthreads();
      f32x4 acc;
      if(w==0)      acc=mfma_unit(Wih1b,xbf,lb,l,0,16);
      else if(w==1) acc=mfma_unit(Whh1b,hbf,lb,l,0,16);
      else if(w==2) acc=mfma_unit(Whh0b,xbf,lb,l,0,8);
      else          acc=mfma_unit(Whh0b,xbf,lb,l,256,8);
      {
        float* gld=gl+w*256;
        #pragma unroll
        for(int r=0;r<4;++r) gld[((l>>4)*4+r)*16+(l&15)]=acc[r];
      }
      __syncthreads();
      gp[tid]=gl[512+tid]+gl[768+tid];      // Whh0 k-halves combined
      if(u>0 && tid<32){
        int j=lb*4+jj;
        float gv[4];
        #pragma unroll
        for(int g=0;g<4;++g){
          int ridx=g*4+jj, row=g*512+j;
          gv[g]=gl[ridx*16+b]+gl[256+ridx*16+b]+b_ih1[row]+b_hh1[row];
        }
        float i_=sigm(gv[0]), f_=sigm(gv[1]), g_=tanhf(gv[2]), o_=sigm(gv[3]);
        c1r=f_*c1r+i_*g_;
        float h=o_*tanhf(c1r);
        gstore(h1new+b*512+j,h);
        hdec[((size_t)(b*64+(u-1)))*512+j]=h;
      }
      if(u==U_) break;
      gridbar(barcnt,bid,++baridx);   // X -> Z

      // ---- Z step 1: combine e-partials + in-block softmax -> w_lds ----
      {
        f32x4 r0[8], r1[8];
        #pragma unroll
        for(int c=0;c<8;++c){
          const float* ep=e_part+(size_t)(c*8+sb)*256+ln2*8;
          r0[c]=gload4(ep); r1[c]=gload4(ep+4);
        }
        GWAIT();
        f32x4 s0=r0[0], s1=r1[0];
        #pragma unroll
        for(int c=1;c<8;++c){ s0+=r0[c]; s1+=r1[c]; }
        float ev[8];
        #pragma unroll
        for(int i=0;i<4;++i){ ev[i]=s0[i]; ev[4+i]=s1[i]; }
        int t0=ln2*8;
        #pragma unroll
        for(int i=0;i<8;++i) if(t0+i>=hl_sb) ev[i]=-1e30f;
        float mloc=ev[0];
        #pragma unroll
        for(int i=1;i<8;++i) mloc=fmaxf(mloc,ev[i]);
        float M=wredmax32(mloc);
        float ssum=0.f;
        #pragma unroll
        for(int i=0;i<8;++i){ ev[i]=expf(ev[i]-M); ssum+=ev[i]; }
        float S=wredsum32(ssum);
        float rS=1.f/S;
        float* wd=w_lds+sb*260+t0;
        #pragma unroll
        for(int i=0;i<8;++i) wd[i]=ev[i]*rS;
      }
      __syncthreads();
      // ---- Z step 2: gates0 partial = sum_t w[b][t]*hsWi0[row][b][t] ----
      {
        int out=tid>>1, half=tid&1;
        int ridx=out>>3, bb=out&7;
        int rowg=(ridx>>2)*512 + lb*4 + (ridx&3);
        const u16* hp=hsWi0T+(size_t)rowg*2048 + bb*256 + half*128;
        const float* wl=w_lds + bb*260 + half*128;
        float p0=0.f,p1=0.f,p2=0.f,p3=0.f;
        #pragma unroll
        for(int i=0;i<16;++i){
          u16x8 v=*(const u16x8*)(hp+i*8);
          f32x4 wa=*(const f32x4*)(wl+i*8), wb4=*(const f32x4*)(wl+i*8+4);
          p0+=wa[0]*bf2f(v[0])+wa[2]*bf2f(v[2]);
          p1+=wa[1]*bf2f(v[1])+wa[3]*bf2f(v[3]);
          p2+=wb4[0]*bf2f(v[4])+wb4[2]*bf2f(v[6]);
          p3+=wb4[1]*bf2f(v[5])+wb4[3]*bf2f(v[7]);
        }
        zres[tid]=(p0+p1)+(p2+p3);
      }
      __syncthreads();
      if(tid<32){
        int j=lb*4+jj;
        float gv[4];
        #pragma unroll
        for(int g=0;g<4;++g){
          int ridx=g*4+jj, row=g*512+j, out=ridx*8+b;
          gv[g]=zres[out*2]+zres[out*2+1]+gp[ridx*16+b]
               +ey_pre[((size_t)((b<<6)|u))*2048+row];
        }
        float i_=sigm(gv[0]), f_=sigm(gv[1]), g_=tanhf(gv[2]), o_=sigm(gv[3]);
        c0r=f_*c0r+i_*g_;
        gstore(h0g+b*512+j,o_*tanhf(c0r));
      }
      gridbar(barcnt,bid,++baridx);   // Z -> next X
    }
  } else {
    // ---- attention block: batch b, a-chunk c: q-chunk + e-partials ----
    int k=bid-128, b=k>>3, c=k&7;
    float* h0s  =(float*)smraw;          // 512 f
    float* qpart=(float*)(smraw+2048);   // 256 f
    float* qs   =(float*)(smraw+3072);   // 64 f
    for(int u=0;u<=U_;++u){
      if(u<U_){
        if(tid<128){
          f32x4 v=gload4(h0g+b*512+tid*4);
          GWAIT();
          *(f32x4*)(h0s+tid*4)=v;
        }
        __syncthreads();
        {
          int al=tid&63, ks=tid>>6;
          const u16* wr=WdT+(size_t)(c*64+al)*512 + ks*128;
          const float* xr=h0s+ks*128;
          float p0=0.f,p1=0.f,p2=0.f,p3=0.f;
          for(int kc=0;kc<16;++kc){
            u16x8 v=*(const u16x8*)(wr+kc*8);
            f32x4 xa=*(const f32x4*)(xr+kc*8), xb2=*(const f32x4*)(xr+kc*8+4);
            p0+=bf2f(v[0])*xa[0]+bf2f(v[2])*xa[2];
            p1+=bf2f(v[1])*xa[1]+bf2f(v[3])*xa[3];
            p2+=bf2f(v[4])*xb2[0]+bf2f(v[6])*xb2[2];
            p3+=bf2f(v[5])*xb2[1]+bf2f(v[7])*xb2[3];
          }
          qpart[(tid>>6)*64+al]=(p0+p1)+(p2+p3);
        }
        __syncthreads();
        if(tid<64) qs[tid]=tanhf(qpart[tid]+qpart[64+tid]+qpart[128+tid]+qpart[192+tid]
                                 +b_att_dec[c*64+tid]);
        __syncthreads();
        {
          // e_part[c][b][t=tid] over this block's 64 a's (lanes t-consecutive)
          const u16* pT=peT+(size_t)b*131072 + (size_t)(c*64)*256 + tid;
          float e0=0.f,e1=0.f,e2=0.f,e3=0.f;
          for(int j=0;j<64;j+=4){
            f32x4 q4=*(const f32x4*)(qs+j);
            e0+=q4[0]*bf2f(pT[(size_t)(j  )*256]);
            e1+=q4[1]*bf2f(pT[(size_t)(j+1)*256]);
            e2+=q4[2]*bf2f(pT[(size_t)(j+2)*256]);
            e3+=q4[3]*bf2f(pT[(size_t)(j+3)*256]);
          }
          gstore(e_part+(size_t)(c*8+b)*256+tid,(e0+e1)+(e2+e3));
        }
      }
      if(u==U_) break;
      gridbar(barcnt,bid,++baridx);   // X -> Z
      gridbar(barcnt,bid,++baridx);   // Z -> next X (attn idle in Z)
    }
  }
}

// ---------------- joint network ----------------
// 32-row t-tiles (33KB LDS -> 2 blocks/CU for latency hiding)
__global__ __launch_bounds__(256) void k_joint(
  const float* __restrict__ lin_enc, const float* __restrict__ lin_dec,
  const u16* __restrict__ WoT, const float* __restrict__ b_out,
  float* __restrict__ out)
{
  __shared__ __align__(16) u16 As[32*512];
  __shared__ float ld_s[512];
  int tid=threadIdx.x, bid=blockIdx.x;
  int b=bid>>9, u=(bid>>3)&63, t0=(bid&7)*32;
  for(int i=tid;i<512;i+=256) ld_s[i]=lin_dec[((size_t)((b<<6)|u))*512 + i];
  __syncthreads();
  const float* le = lin_enc + ((size_t)(b*256 + t0))*512;
  for(int it=0;it<8;++it){
    int idx=it*256+tid;
    int row=idx>>6, c0=(idx&63)*8;
    f32x4 x0=*(const f32x4*)(le + (size_t)row*512 + c0);
    f32x4 x1=*(const f32x4*)(le + (size_t)row*512 + c0 + 4);
    u16x8 pk;
    #pragma unroll
    for(int i=0;i<4;++i){
      pk[i]  =f2bf(tanhf(x0[i]+ld_s[c0+i]));
      pk[4+i]=f2bf(tanhf(x1[i]+ld_s[c0+4+i]));
    }
    int sc = c0 ^ ((row&7)<<3);
    *(u16x8*)&As[row*512+sc]=pk;
  }
  __syncthreads();
  int w=tid>>6, l=tid&63;
  for(int ch=0;ch<8;++ch){
    int n0=ch*64 + w*16;
    int o = n0 + (l&15);
    s16x8 bfr[16];
    const u16* wp = WoT + (size_t)o*512 + ((l>>4)*8);
    #pragma unroll
    for(int ks=0;ks<16;++ks) bfr[ks]=*(const s16x8*)(wp + ks*32);
    float bo = (o<OD)? b_out[o] : 0.f;
    #pragma unroll
    for(int mt=0;mt<2;++mt){
      f32x4 acc=(f32x4){0.f,0.f,0.f,0.f};
      int row = mt*16 + (l&15);
      int sw  = (row&7)<<3;
      #pragma unroll
      for(int ks=0;ks<16;++ks){
        int cidx=(ks*32 + (l>>4)*8) ^ sw;
        s16x8 af=*(const s16x8*)&As[row*512+cidx];
        acc=__builtin_amdgcn_mfma_f32_16x16x32_bf16(af,bfr[ks],acc,0,0,0);
      }
      if(o<OD){
        #pragma unroll
        for(int r=0;r<4;++r){
          int t = t0 + mt*16 + ((l>>4)<<2) + r;
          out[(((size_t)(b*256+t))*64 + u)*500 + o] = acc[r] + bo;
        }
      }
    }
  }
}

// ---------------- host launcher ----------------
extern "C" void kernel_launch(void* const* d_in, const int* in_sizes, int n_in,
                              void* d_out, int out_size, void* d_ws, size_t ws_size,
                              hipStream_t stream)
{
  (void)in_sizes; (void)n_in; (void)out_size; (void)ws_size;
  const float* hs_pad   =(const float*)d_in[0];
  const int*   ys       =(const int*)  d_in[1];
  const int*   hlens    =(const int*)  d_in[2];
  const float* emb      =(const float*)d_in[3];
  const float* W_ih0    =(const float*)d_in[4];
  const float* W_hh0    =(const float*)d_in[5];
  const float* b_ih0    =(const float*)d_in[6];
  const float* b_hh0    =(const float*)d_in[7];
  const float* W_ih1    =(const float*)d_in[8];
  const float* W_hh1    =(const float*)d_in[9];
  const float* b_ih1    =(const float*)d_in[10];
  const float* b_hh1    =(const float*)d_in[11];
  const float* W_att_enc=(const float*)d_in[12];
  const float* b_att_enc=(const float*)d_in[13];
  const float* W_att_dec=(const float*)d_in[14];
  const float* b_att_dec=(const float*)d_in[15];
  const float* W_lin_enc=(const float*)d_in[16];
  const float* b_lin_enc=(const float*)d_in[17];
  const float* W_lin_dec=(const float*)d_in[18];
  const float* W_out    =(const float*)d_in[19];
  const float* b_out    =(const float*)d_in[20];
  float* out=(float*)d_out;

  char* wp=(char*)d_ws;
  auto carve=[&](size_t bytes)->char*{ char* p=wp; wp += (bytes+255)&~(size_t)255; return p; };
  u16*   pe_bf  =(u16*)  carve((size_t)B_*T_*D_*2);
  u16*   peT    =(u16*)  carve((size_t)B_*D_*T_*2);
  u16*   WdT    =(u16*)  carve((size_t)512*512*2);
  u16*   Whh0b  =(u16*)  carve((size_t)G_*512*2);
  u16*   Wih1b  =(u16*)  carve((size_t)G_*512*2);
  u16*   Whh1b  =(u16*)  carve((size_t)G_*512*2);
  u16*   WoT    =(u16*)  carve((size_t)512*512*2);
  u16*   hsWi0T =(u16*)  carve((size_t)G_*B_*T_*2);   // [row][b*256+t] bf16, 8MB
  float* lin_enc=(float*)carve((size_t)B_*T_*512*4);
  float* ey_pre =(float*)carve((size_t)B_*U_*G_*4);
  float* hdec   =(float*)carve((size_t)B_*U_*512*4);
  float* lin_dec=(float*)carve((size_t)B_*U_*512*4);
  float* e_part =(float*)carve((size_t)8*8*256*4);
  float* states =(float*)carve(3*4096*4);
  unsigned* barcnt=(unsigned*)carve(2048);
  float* h0g=states;            // 4096
  float* h1g=states+4096;       // 2 x 4096 (ping-pong)

  hipMemsetAsync(states,0,3*4096*4,stream);
  hipMemsetAsync(barcnt,0,2048,stream);

  int n2=G_*512;
  k_trans_bf<<<(512*512+255)/256,256,0,stream>>>(W_att_dec,WdT,512,512);
  k_f2bf    <<<(n2+255)/256,256,0,stream>>>(W_hh0,Whh0b,n2);
  k_f2bf    <<<(n2+255)/256,256,0,stream>>>(W_ih1,Wih1b,n2);
  k_f2bf    <<<(n2+255)/256,256,0,stream>>>(W_hh1,Whh1b,n2);
  k_woT     <<<(512*512+255)/256,256,0,stream>>>(W_out,WoT);

  // pre GEMMs
  k_gemm<<<dim3(32,8),256,0,stream>>>(hs_pad,nullptr,512, W_att_enc,512,0, b_att_enc,nullptr, 1,1, pe_bf,512, 512);
  k_peT <<<(B_*512*T_+255)/256,256,0,stream>>>(pe_bf,peT);
  k_gemm<<<dim3(32,8),256,0,stream>>>(hs_pad,nullptr,512, W_lin_enc,512,0, b_lin_enc,nullptr, 0,0, lin_enc,512, 512);
  k_gemm<<<dim3(8,32),256,0,stream>>>(emb,ys,512,        W_ih0,1024,1,    b_ih0,b_hh0,      0,0, ey_pre,2048, 512);
  // hsWi0T[row][b,t] = W_ih0[row][512:1024] . hs_pad[b,t,:]  (M=2048,N=2048,K=512)
  k_gemm<<<dim3(32,32),256,0,stream>>>(W_ih0+512,nullptr,1024, hs_pad,512,1, nullptr,nullptr, 0,1, hsWi0T,2048, 512);

  // persistent scan: one launch for all 64 steps
  k_scan<<<NBLK,256,0,stream>>>(WdT,b_att_dec,peT,hlens,
                                hsWi0T,Whh0b,Wih1b,Whh1b,b_ih1,b_hh1,ey_pre,
                                e_part,h0g,h1g,hdec,barcnt);

  // post GEMM + joint
  k_gemm <<<dim3(8,8),256,0,stream>>>(hdec,nullptr,512, W_lin_dec,512,0, nullptr,nullptr, 0,0, lin_dec,512, 512);
  k_joint<<<4096,256,0,stream>>>(lin_enc,lin_dec,WoT,b_out,out);
}